// Round 7
// baseline (497.510 us; speedup 1.0000x reference)
//
#include <hip/hip_runtime.h>
#include <cstdint>

typedef unsigned short ushort_t;
typedef __attribute__((ext_vector_type(8))) short v8s;
typedef __attribute__((ext_vector_type(4))) short v4s;
typedef __attribute__((ext_vector_type(2))) unsigned v2u;
typedef __attribute__((ext_vector_type(4))) float v4f;

#define MFMA(a, b, c) __builtin_amdgcn_mfma_f32_16x16x32_bf16(a, b, c, 0, 0, 0)

__device__ __forceinline__ float bf2f(ushort_t u) {
    union { unsigned u; float f; } x; x.u = ((unsigned)u) << 16; return x.f;
}
__device__ __forceinline__ short f2bf(float f) {
    union { float f; unsigned u; } x; x.f = f;
    unsigned r = x.u + 0x7fffu + ((x.u >> 16) & 1u);   // RNE
    return (short)(r >> 16);
}

// ---------------- dtype detect: flag=1 if x is bf16-packed, 0 if fp32 ----------------
__global__ void detect_dtype(const unsigned* __restrict__ x, int* __restrict__ flag) {
    __shared__ int cnt;
    if (threadIdx.x == 0) cnt = 0;
    __syncthreads();
    unsigned w = x[threadIdx.x];
    int e = (w >> 7) & 0xFF;
    int hit = ((e >= 96 && e <= 135) || (w & 0xFFFFu) == 0) ? 1 : 0;
    atomicAdd(&cnt, hit);
    __syncthreads();
    if (threadIdx.x == 0) *flag = (cnt >= 160) ? 1 : 0;
}

// ---------------- convert x -> internal bf16 (8 elems/thread) ----------------
__global__ __launch_bounds__(256) void cvt_x(const void* __restrict__ xin,
                                             ushort_t* __restrict__ xb,
                                             const int* __restrict__ flagp, int n8) {
    int i = blockIdx.x * 256 + threadIdx.x;
    if (i >= n8) return;
    if (*flagp) {
        ((v8s*)xb)[i] = ((const v8s*)xin)[i];
    } else {
        const float* xf = (const float*)xin + (size_t)i * 8;
        v8s o;
        #pragma unroll
        for (int j = 0; j < 8; ++j) o[j] = f2bf(xf[j]);
        ((v8s*)xb)[i] = o;
    }
}

// ---------------- convert + transpose weights: out[c][r] = bf16(in[r][c]) ----------------
__global__ __launch_bounds__(256) void cvt_transpose(const void* __restrict__ in,
                                                     ushort_t* __restrict__ out,
                                                     const int* __restrict__ flagp,
                                                     int R, int C) {
    __shared__ ushort_t tile[32][33];
    int bx = blockIdx.x * 32, by = blockIdx.y * 32;
    int tx = threadIdx.x, ty = threadIdx.y;
    int isbf = *flagp;
    for (int i = ty; i < 32; i += 8) {
        size_t idx = (size_t)(by + i) * C + bx + tx;
        tile[i][tx] = isbf ? ((const ushort_t*)in)[idx]
                           : (ushort_t)f2bf(((const float*)in)[idx]);
    }
    __syncthreads();
    for (int i = ty; i < 32; i += 8) out[(size_t)(bx + i) * R + by + tx] = tile[tx][i];
}

// ---------------- GEMM: C[M][N] = A[M][K] * BT[N][K]^T, bf16 in ----------------
template <int OUTMODE>
__global__ __launch_bounds__(256) void gemm_bt(const ushort_t* __restrict__ A,
                                               const ushort_t* __restrict__ BT,
                                               void* __restrict__ C,
                                               const int* __restrict__ flagp,
                                               int M, int N, int K) {
    __shared__ __align__(16) ushort_t As[128 * 32];
    __shared__ __align__(16) ushort_t Bs[128 * 32];
    int tid = threadIdx.x;
    int lane = tid & 63;
    int lr = lane & 15, lc = lane >> 4;
    int w = tid >> 6;
    int wr = (w >> 1) * 64, wc = (w & 1) * 64;
    int m0 = blockIdx.y * 128, n0 = blockIdx.x * 128;

    int c0 = tid, c1 = tid + 256;
    int r0 = c0 >> 2, s0 = c0 & 3;
    int r1 = c1 >> 2, s1 = c1 & 3;

    v4f acc[4][4] = {};

    for (int kt = 0; kt < K; kt += 32) {
        v8s a0 = *(const v8s*)(A + (size_t)(m0 + r0) * K + kt + s0 * 8);
        v8s a1 = *(const v8s*)(A + (size_t)(m0 + r1) * K + kt + s1 * 8);
        v8s b0 = *(const v8s*)(BT + (size_t)(n0 + r0) * K + kt + s0 * 8);
        v8s b1 = *(const v8s*)(BT + (size_t)(n0 + r1) * K + kt + s1 * 8);
        __syncthreads();
        *(v8s*)(As + (size_t)c0 * 8) = a0;
        *(v8s*)(As + (size_t)c1 * 8) = a1;
        *(v8s*)(Bs + (size_t)c0 * 8) = b0;
        *(v8s*)(Bs + (size_t)c1 * 8) = b1;
        __syncthreads();

        v8s af[4], bfr[4];
        #pragma unroll
        for (int i = 0; i < 4; ++i)
            af[i] = *(const v8s*)(As + (wr + i * 16 + lr) * 32 + lc * 8);
        #pragma unroll
        for (int j = 0; j < 4; ++j)
            bfr[j] = *(const v8s*)(Bs + (wc + j * 16 + lr) * 32 + lc * 8);
        #pragma unroll
        for (int i = 0; i < 4; ++i)
            #pragma unroll
            for (int j = 0; j < 4; ++j)
                acc[i][j] = MFMA(af[i], bfr[j], acc[i][j]);
    }
    int store_f32 = (OUTMODE == 1) && (*flagp == 0);
    #pragma unroll
    for (int i = 0; i < 4; ++i)
        #pragma unroll
        for (int j = 0; j < 4; ++j)
            #pragma unroll
            for (int r = 0; r < 4; ++r) {
                int row = m0 + wr + i * 16 + lc * 4 + r;
                int col = n0 + wc + j * 16 + lr;
                if (store_f32)
                    ((float*)C)[(size_t)row * N + col] = acc[i][j][r];
                else
                    ((ushort_t*)C)[(size_t)row * N + col] = (ushort_t)f2bf(acc[i][j][r]);
            }
}

// ---------------- RoPE table: tab[t][0:32]=cos(bf16-rounded), [32:64]=sin ----------------
__global__ __launch_bounds__(256) void rope_table(float* __restrict__ tab) {
    int idx = blockIdx.x * 256 + threadIdx.x;   // 65536 = 2048*32
    int t = idx >> 5, d = idx & 31;
    float inv_freq = __expf(-(float)d * 0.28782313662425575f);  // 10000^(-d/32)
    float ang = (float)t * inv_freq;
    float sn, cs;
    sincosf(ang, &sn, &cs);
    tab[t * 64 + d]      = bf2f((ushort_t)f2bf(cs));
    tab[t * 64 + 32 + d] = bf2f((ushort_t)f2bf(sn));
}

// ---------------- RoPE + reshape ----------------
// Q scale folds 1/sqrt(64) AND log2(e) so attn uses raw exp2.
// V written TILED: Vt[bh][s_tile(64)][d(64)][s_in_tile(32)]
#define QSCALE 0.18033688011112042f
__global__ __launch_bounds__(256) void rope_reshape(const ushort_t* __restrict__ qkv,
                                                    const float* __restrict__ tab,
                                                    ushort_t* __restrict__ Qr,
                                                    ushort_t* __restrict__ Kr,
                                                    ushort_t* __restrict__ Vt) {
    __shared__ __align__(16) ushort_t Vl[64][72];
    int tid = threadIdx.x;
    int tq = tid >> 2, dc = tid & 3;
    int t0 = blockIdx.x * 64;
    int bh = blockIdx.y;
    int b = bh >> 4, h = bh & 15;
    int t = t0 + tq;
    size_t rb = ((size_t)(b * 2048 + t)) * 3072 + h * 64;

    v8s qlo = *(const v8s*)(qkv + rb + dc * 8);
    v8s qhi = *(const v8s*)(qkv + rb + dc * 8 + 32);
    v8s klo = *(const v8s*)(qkv + rb + 1024 + dc * 8);
    v8s khi = *(const v8s*)(qkv + rb + 1024 + dc * 8 + 32);
    v8s vlo = *(const v8s*)(qkv + rb + 2048 + dc * 8);
    v8s vhi = *(const v8s*)(qkv + rb + 2048 + dc * 8 + 32);

    const float* ct = tab + t * 64 + dc * 8;
    v8s qolo, qohi, kolo, kohi;
    #pragma unroll
    for (int j = 0; j < 8; ++j) {
        float cb = ct[j], sb = ct[32 + j];
        float x1 = bf2f((ushort_t)qlo[j]), x2 = bf2f((ushort_t)qhi[j]);
        qolo[j] = f2bf((x1 * cb - x2 * sb) * QSCALE);
        qohi[j] = f2bf((x2 * cb + x1 * sb) * QSCALE);
        float k1 = bf2f((ushort_t)klo[j]), k2 = bf2f((ushort_t)khi[j]);
        kolo[j] = f2bf(k1 * cb - k2 * sb);
        kohi[j] = f2bf(k2 * cb + k1 * sb);
    }
    size_t ob = ((size_t)bh * 2048 + t) * 64;
    *(v8s*)(Qr + ob + dc * 8) = qolo;
    *(v8s*)(Qr + ob + dc * 8 + 32) = qohi;
    *(v8s*)(Kr + ob + dc * 8) = kolo;
    *(v8s*)(Kr + ob + dc * 8 + 32) = kohi;

    *(v8s*)(&Vl[tq][dc * 8]) = vlo;
    *(v8s*)(&Vl[tq][dc * 8 + 32]) = vhi;
    __syncthreads();
    int d = tid >> 2, tc = tid & 3;
    v8s o1, o2;
    #pragma unroll
    for (int k = 0; k < 8; ++k) o1[k] = (short)Vl[tc * 16 + k][d];
    #pragma unroll
    for (int k = 0; k < 8; ++k) o2[k] = (short)Vl[tc * 16 + 8 + k][d];
    size_t vb = (size_t)bh * 131072 + (size_t)((t0 >> 5) + (tc >> 1)) * 2048
              + d * 32 + (tc & 1) * 16;
    *(v8s*)(Vt + vb) = o1;
    *(v8s*)(Vt + vb + 8) = o2;
}

// ---------------- flash attention: 4 waves/block, 64 q/block, s-split x4 ----------------
// XCD-local work claiming via HW_REG_XCC_ID + per-XCD atomic counters (L2-resident KV).
// S^T = K*Q^T (stats lane-local in q). No-max exp2 softmax. Software-pipelined step:
// K 2-ahead, QK(t+1) overlaps P(t) LDS round trip (parity-double-buffered P).
__global__ __launch_bounds__(256, 3) void attn(const ushort_t* __restrict__ Qr,
                                               const ushort_t* __restrict__ Kr,
                                               const ushort_t* __restrict__ Vt,
                                               ushort_t* __restrict__ AO,
                                               int* __restrict__ ctr) {
    __shared__ __align__(16) ushort_t P[4 * 2 * 2560];   // 40960 B; merge bufs alias after loop
    __shared__ float LiA[64], LiB[64];
    __shared__ int s_item;
    int tid = threadIdx.x, lane = tid & 63, W = tid >> 6;
    int lr = lane & 15, lc = lane >> 4;

    unsigned xcc;
    asm volatile("s_getreg_b32 %0, hwreg(20, 0, 4)" : "=s"(xcc));   // HW_REG_XCC_ID
    if (tid == 0) {
        int item = -1;
        #pragma unroll 1
        for (int j = 0; j < 8; ++j) {
            int x = ((int)xcc + j) & 7;
            int idx = atomicAdd(&ctr[x], 1);
            if (idx < 128) { item = x * 128 + idx; break; }
        }
        s_item = item;
    }
    __syncthreads();
    int item = s_item;
    if (item < 0) return;
    int bh = item >> 5;              // = xcd*4 + local_idx/32
    int q0 = (item & 31) * 64;
    int b = bh >> 4, h = bh & 15;

    const ushort_t* Qb = Qr + ((size_t)bh * 2048 + q0) * 64;
    const ushort_t* Kp = Kr + (size_t)bh * 131072 + (size_t)W * 32768 + lr * 64 + lc * 8;
    const ushort_t* Vp = Vt + (size_t)bh * 131072 + (size_t)W * 32768 + lr * 32 + lc * 8;

    v8s qf[4][2];
    #pragma unroll
    for (int jq = 0; jq < 4; ++jq)
        #pragma unroll
        for (int kk = 0; kk < 2; ++kk)
            qf[jq][kk] = *(const v8s*)(Qb + (size_t)(jq * 16 + lr) * 64 + kk * 32 + lc * 8);

    v4f o[4][4] = {};
    float li[4] = {0.f, 0.f, 0.f, 0.f};

    auto loadK = [&](v8s (&kf)[2][2], int stp) {
        #pragma unroll
        for (int hh = 0; hh < 2; ++hh)
            #pragma unroll
            for (int kk = 0; kk < 2; ++kk)
                kf[hh][kk] = *(const v8s*)(Kp + (size_t)stp * 2048 + hh * 1024 + kk * 32);
    };
    auto loadV = [&](v8s (&vf)[4], int stp) {
        #pragma unroll
        for (int i = 0; i < 4; ++i)
            vf[i] = *(const v8s*)(Vp + (size_t)stp * 2048 + i * 512);
    };
    auto qk = [&](v4f (&S)[2][4], v8s (&kf)[2][2]) {
        #pragma unroll
        for (int hh = 0; hh < 2; ++hh)
            #pragma unroll
            for (int jq = 0; jq < 4; ++jq) {
                v4f z = {0.f, 0.f, 0.f, 0.f};
                z = MFMA(kf[hh][0], qf[jq][0], z);
                S[hh][jq] = MFMA(kf[hh][1], qf[jq][1], z);
            }
    };
    auto exp_pack = [&](v4f (&S)[2][4], ushort_t* Pw) {
        #pragma unroll
        for (int jq = 0; jq < 4; ++jq)
            #pragma unroll
            for (int hh = 0; hh < 2; ++hh) {
                #pragma unroll
                for (int r = 0; r < 4; ++r) {
                    float ev = __builtin_amdgcn_exp2f(S[hh][jq][r]);
                    S[hh][jq][r] = ev;
                    li[jq] += ev;
                }
                unsigned d0 = __builtin_amdgcn_perm(__float_as_uint(S[hh][jq][1]),
                                                    __float_as_uint(S[hh][jq][0]), 0x07060302u);
                unsigned d1 = __builtin_amdgcn_perm(__float_as_uint(S[hh][jq][3]),
                                                    __float_as_uint(S[hh][jq][2]), 0x07060302u);
                v2u pk = {d0, d1};
                *(v2u*)(Pw + (jq * 16 + lr) * 40 + hh * 16 + lc * 4) = pk;
            }
    };
    auto pv = [&](ushort_t* Pw, v8s (&vf)[4]) {
        #pragma unroll
        for (int jq = 0; jq < 4; ++jq) {
            v8s pf = *(const v8s*)(Pw + (jq * 16 + lr) * 40 + lc * 8);
            #pragma unroll
            for (int i = 0; i < 4; ++i)
                o[i][jq] = MFMA(vf[i], pf, o[i][jq]);
        }
    };

    v8s kb[2][2][2], vb[2][4];
    v4f Sb[2][2][4];
    loadK(kb[0], 0); loadV(vb[0], 0);
    loadK(kb[1], 1); loadV(vb[1], 1);
    qk(Sb[0], kb[0]);

    #pragma unroll
    for (int t = 0; t < 16; ++t) {
        int p = t & 1, pn = p ^ 1;
        ushort_t* Pw = P + (W * 2 + p) * 2560;
        if (t + 2 < 16) loadK(kb[p], t + 2);       // kb[p] held K(t), consumed by Sb[p]
        exp_pack(Sb[p], Pw);                       // frees Sb[p]
        if (t + 1 < 16) qk(Sb[pn], kb[pn]);        // overlaps the P LDS round trip
        __builtin_amdgcn_s_waitcnt(0xc07f);        // lgkmcnt(0) only; vm prefetch stays in flight
        pv(Pw, vb[p]);
        if (t + 2 < 16) loadV(vb[p], t + 2);       // vb[p] (=V(t)) now dead
    }

    // li wave-reduce (lc quarters duplicate q columns)
    #pragma unroll
    for (int jq = 0; jq < 4; ++jq) {
        li[jq] += __shfl_xor(li[jq], 16);
        li[jq] += __shfl_xor(li[jq], 32);
    }
    // merge tree: (W1->A, W3->B); (W0+=A, W2+=B); (W2->A); (W0+=A, store)
    float* bufA = (float*)P;                         // 64 x 68 fp32 = 17408 B
    float* bufB = (float*)((char*)P + 17408);
    __syncthreads();
    if (W == 1 || W == 3) {
        float* buf = (W == 1) ? bufA : bufB;
        float* Lb  = (W == 1) ? LiA : LiB;
        #pragma unroll
        for (int jq = 0; jq < 4; ++jq) {
            #pragma unroll
            for (int i = 0; i < 4; ++i)
                *(v4f*)(buf + (jq * 16 + lr) * 68 + i * 16 + lc * 4) = o[i][jq];
            if (lc == 0) Lb[jq * 16 + lr] = li[jq];
        }
    }
    __syncthreads();
    if (W == 0 || W == 2) {
        float* buf = (W == 0) ? bufA : bufB;
        float* Lb  = (W == 0) ? LiA : LiB;
        #pragma unroll
        for (int jq = 0; jq < 4; ++jq) {
            li[jq] += Lb[jq * 16 + lr];
            #pragma unroll
            for (int i = 0; i < 4; ++i) {
                v4f m = *(const v4f*)(buf + (jq * 16 + lr) * 68 + i * 16 + lc * 4);
                #pragma unroll
                for (int r = 0; r < 4; ++r) o[i][jq][r] += m[r];
            }
        }
    }
    __syncthreads();
    if (W == 2) {
        #pragma unroll
        for (int jq = 0; jq < 4; ++jq) {
            #pragma unroll
            for (int i = 0; i < 4; ++i)
                *(v4f*)(bufA + (jq * 16 + lr) * 68 + i * 16 + lc * 4) = o[i][jq];
            if (lc == 0) LiA[jq * 16 + lr] = li[jq];
        }
    }
    __syncthreads();
    if (W == 0) {
        #pragma unroll
        for (int jq = 0; jq < 4; ++jq) {
            float inv = 1.0f / (li[jq] + LiA[jq * 16 + lr]);
            int t = q0 + jq * 16 + lr;
            #pragma unroll
            for (int i = 0; i < 4; ++i) {
                v4f m = *(const v4f*)(bufA + (jq * 16 + lr) * 68 + i * 16 + lc * 4);
                v4s pk;
                #pragma unroll
                for (int r = 0; r < 4; ++r) pk[r] = f2bf((o[i][jq][r] + m[r]) * inv);
                *(v4s*)(AO + (size_t)(b * 2048 + t) * 1024 + h * 64 + i * 16 + lc * 4) = pk;
            }
        }
    }
}

extern "C" void kernel_launch(void* const* d_in, const int* in_sizes, int n_in,
                              void* d_out, int out_size, void* d_ws, size_t ws_size,
                              hipStream_t stream) {
    char* ws = (char*)d_ws;
    int*      flag  = (int*)ws;                     // [0,4)
    int*      ctr   = (int*)(ws + 64);              // 8 per-XCD work counters
    ushort_t* wqkvT = (ushort_t*)(ws + 256);
    ushort_t* woT   = (ushort_t*)(ws + 6291712);
    ushort_t* xb    = (ushort_t*)(ws + 8388864);
    ushort_t* qkv   = (ushort_t*)(ws + 16777472);
    ushort_t* Qr    = (ushort_t*)(ws + 41943296);
    ushort_t* Vt    = (ushort_t*)(ws + 50331904);
    float*    tab   = (float*)(ws + 58720512);      // 512 KB rope table
    ushort_t* Kr    = xb;     // reuse
    ushort_t* AO    = qkv;    // reuse

    hipMemsetAsync(ctr, 0, 32, stream);
    detect_dtype<<<1, 256, 0, stream>>>((const unsigned*)d_in[0], flag);
    rope_table<<<256, 256, 0, stream>>>(tab);
    cvt_x<<<2048, 256, 0, stream>>>(d_in[0], xb, flag, 524288);
    dim3 tb(32, 8);
    cvt_transpose<<<dim3(96, 32), tb, 0, stream>>>(d_in[1], wqkvT, flag, 1024, 3072);
    cvt_transpose<<<dim3(32, 32), tb, 0, stream>>>(d_in[2], woT, flag, 1024, 1024);
    gemm_bt<0><<<dim3(24, 32), 256, 0, stream>>>(xb, wqkvT, qkv, flag, 4096, 3072, 1024);
    rope_reshape<<<dim3(32, 32), 256, 0, stream>>>(qkv, tab, Qr, Kr, Vt);
    attn<<<1024, 256, 0, stream>>>(Qr, Kr, Vt, AO, ctr);
    gemm_bt<1><<<dim3(8, 32), 256, 0, stream>>>(AO, woT, d_out, flag, 4096, 1024, 1024);
}

// Round 8
// 217.407 us; speedup vs baseline: 2.2884x; 2.2884x over previous
//
#include <hip/hip_runtime.h>
#include <cstdint>

typedef unsigned short ushort_t;
typedef __attribute__((ext_vector_type(8))) short v8s;
typedef __attribute__((ext_vector_type(4))) short v4s;
typedef __attribute__((ext_vector_type(2))) unsigned v2u;
typedef __attribute__((ext_vector_type(4))) float v4f;

#define MFMA(a, b, c) __builtin_amdgcn_mfma_f32_16x16x32_bf16(a, b, c, 0, 0, 0)
#define QSCALE 0.18033688011112042f   // (1/8) * log2(e): attn softmax runs in exp2 space

__device__ __forceinline__ float bf2f(ushort_t u) {
    union { unsigned u; float f; } x; x.u = ((unsigned)u) << 16; return x.f;
}
__device__ __forceinline__ short f2bf(float f) {
    union { float f; unsigned u; } x; x.f = f;
    unsigned r = x.u + 0x7fffu + ((x.u >> 16) & 1u);   // RNE
    return (short)(r >> 16);
}

// ---------------- dtype detect: flag=1 if x is bf16-packed, 0 if fp32 ----------------
__global__ void detect_dtype(const unsigned* __restrict__ x, int* __restrict__ flag) {
    __shared__ int cnt;
    if (threadIdx.x == 0) cnt = 0;
    __syncthreads();
    unsigned w = x[threadIdx.x];
    int e = (w >> 7) & 0xFF;
    int hit = ((e >= 96 && e <= 135) || (w & 0xFFFFu) == 0) ? 1 : 0;
    atomicAdd(&cnt, hit);
    __syncthreads();
    if (threadIdx.x == 0) *flag = (cnt >= 160) ? 1 : 0;
}

// ---------------- convert x -> internal bf16 (8 elems/thread) ----------------
__global__ __launch_bounds__(256) void cvt_x(const void* __restrict__ xin,
                                             ushort_t* __restrict__ xb,
                                             const int* __restrict__ flagp, int n8) {
    int i = blockIdx.x * 256 + threadIdx.x;
    if (i >= n8) return;
    if (*flagp) {
        ((v8s*)xb)[i] = ((const v8s*)xin)[i];
    } else {
        const float* xf = (const float*)xin + (size_t)i * 8;
        v8s o;
        #pragma unroll
        for (int j = 0; j < 8; ++j) o[j] = f2bf(xf[j]);
        ((v8s*)xb)[i] = o;
    }
}

// ---------------- convert + transpose weights: out[c][r] = bf16(in[r][c]) ----------------
__global__ __launch_bounds__(256) void cvt_transpose(const void* __restrict__ in,
                                                     ushort_t* __restrict__ out,
                                                     const int* __restrict__ flagp,
                                                     int R, int C) {
    __shared__ ushort_t tile[32][33];
    int bx = blockIdx.x * 32, by = blockIdx.y * 32;
    int tx = threadIdx.x, ty = threadIdx.y;
    int isbf = *flagp;
    for (int i = ty; i < 32; i += 8) {
        size_t idx = (size_t)(by + i) * C + bx + tx;
        tile[i][tx] = isbf ? ((const ushort_t*)in)[idx]
                           : (ushort_t)f2bf(((const float*)in)[idx]);
    }
    __syncthreads();
    for (int i = ty; i < 32; i += 8) out[(size_t)(bx + i) * R + by + tx] = tile[tx][i];
}

// ---------------- RoPE table: tab[t][0:32]=cos(bf16-rounded), [32:64]=sin ----------------
__global__ __launch_bounds__(256) void rope_table(float* __restrict__ tab) {
    int idx = blockIdx.x * 256 + threadIdx.x;   // 65536 = 2048*32
    int t = idx >> 5, d = idx & 31;
    float inv_freq = __expf(-(float)d * 0.28782313662425575f);  // 10000^(-d/32)
    float ang = (float)t * inv_freq;
    float sn, cs;
    sincosf(ang, &sn, &cs);
    tab[t * 64 + d]      = bf2f((ushort_t)f2bf(cs));
    tab[t * 64 + 32 + d] = bf2f((ushort_t)f2bf(sn));
}

// ---------------- GEMM: C[M][N] = A[M][K] * BT[N][K]^T, bf16 in ----------------
// MODE 1: C store, fp32 if *flagp==0 else bf16 (out-proj).
// MODE 2: fused RoPE epilogue -> writes Qr (scaled), Kr, Vt (tiled); C unused.
template <int MODE>
__global__ __launch_bounds__(256) void gemm_bt(const ushort_t* __restrict__ A,
                                               const ushort_t* __restrict__ BT,
                                               void* __restrict__ C,
                                               const int* __restrict__ flagp,
                                               int M, int N, int K,
                                               ushort_t* __restrict__ Qp,
                                               ushort_t* __restrict__ Kp,
                                               ushort_t* __restrict__ Vp,
                                               const float* __restrict__ tab) {
    __shared__ __align__(16) ushort_t As[128 * 32];
    __shared__ __align__(16) ushort_t Bs[128 * 32];
    int tid = threadIdx.x;
    int lane = tid & 63;
    int lr = lane & 15, lc = lane >> 4;
    int w = tid >> 6;
    int wr = (w >> 1) * 64, wc = (w & 1) * 64;
    int m0 = blockIdx.y * 128, n0 = blockIdx.x * 128;

    int c0 = tid, c1 = tid + 256;
    int r0 = c0 >> 2, s0 = c0 & 3;
    int r1 = c1 >> 2, s1 = c1 & 3;

    v4f acc[4][4] = {};

    for (int kt = 0; kt < K; kt += 32) {
        v8s a0 = *(const v8s*)(A + (size_t)(m0 + r0) * K + kt + s0 * 8);
        v8s a1 = *(const v8s*)(A + (size_t)(m0 + r1) * K + kt + s1 * 8);
        v8s b0 = *(const v8s*)(BT + (size_t)(n0 + r0) * K + kt + s0 * 8);
        v8s b1 = *(const v8s*)(BT + (size_t)(n0 + r1) * K + kt + s1 * 8);
        __syncthreads();
        *(v8s*)(As + (size_t)c0 * 8) = a0;
        *(v8s*)(As + (size_t)c1 * 8) = a1;
        *(v8s*)(Bs + (size_t)c0 * 8) = b0;
        *(v8s*)(Bs + (size_t)c1 * 8) = b1;
        __syncthreads();

        v8s af[4], bfr[4];
        #pragma unroll
        for (int i = 0; i < 4; ++i)
            af[i] = *(const v8s*)(As + (wr + i * 16 + lr) * 32 + lc * 8);
        #pragma unroll
        for (int j = 0; j < 4; ++j)
            bfr[j] = *(const v8s*)(Bs + (wc + j * 16 + lr) * 32 + lc * 8);
        #pragma unroll
        for (int i = 0; i < 4; ++i)
            #pragma unroll
            for (int j = 0; j < 4; ++j)
                acc[i][j] = MFMA(af[i], bfr[j], acc[i][j]);
    }

    if (MODE == 1) {
        int store_f32 = (*flagp == 0);
        #pragma unroll
        for (int i = 0; i < 4; ++i)
            #pragma unroll
            for (int j = 0; j < 4; ++j)
                #pragma unroll
                for (int r = 0; r < 4; ++r) {
                    int row = m0 + wr + i * 16 + lc * 4 + r;
                    int col = n0 + wc + j * 16 + lr;
                    if (store_f32)
                        ((float*)C)[(size_t)row * N + col] = acc[i][j][r];
                    else
                        ((ushort_t*)C)[(size_t)row * N + col] = (ushort_t)f2bf(acc[i][j][r]);
                }
    } else {  // MODE 2: fused RoPE + reshape epilogue (N=3072 qkv GEMM)
        int region = n0 >> 10;                  // 0=Q 1=K 2=V
        int h = ((n0 & 1023) + wc) >> 6;        // head (j*16+lr < 64 never crosses)
        if (region < 2) {
            const float sc = (region == 0) ? QSCALE : 1.0f;
            ushort_t* dst = (region == 0) ? Qp : Kp;
            #pragma unroll
            for (int i = 0; i < 4; ++i)
                #pragma unroll
                for (int j = 0; j < 2; ++j) {   // d = j*16+lr in [0,32); partner acc[i][j+2] = d+32
                    int d = j * 16 + lr;
                    #pragma unroll
                    for (int r = 0; r < 4; ++r) {
                        int tg = m0 + wr + i * 16 + lc * 4 + r;
                        int b = tg >> 11, tt = tg & 2047;
                        float cs = tab[tt * 64 + d], sn = tab[tt * 64 + 32 + d];
                        float x1 = acc[i][j][r], x2 = acc[i][j + 2][r];
                        size_t base = ((size_t)(b * 16 + h) * 2048 + tt) * 64 + d;
                        dst[base]      = (ushort_t)f2bf((x1 * cs - x2 * sn) * sc);
                        dst[base + 32] = (ushort_t)f2bf((x2 * cs + x1 * sn) * sc);
                    }
                }
        } else {  // V: tiled layout Vt[bh][s_tile][d*32 + s_in_tile], 4 consecutive s per lane
            #pragma unroll
            for (int i = 0; i < 4; ++i)
                #pragma unroll
                for (int j = 0; j < 4; ++j) {
                    int d = j * 16 + lr;
                    int tg0 = m0 + wr + i * 16 + lc * 4;
                    int b = tg0 >> 11, tt = tg0 & 2047;
                    v4s pk;
                    #pragma unroll
                    for (int r = 0; r < 4; ++r) pk[r] = f2bf(acc[i][j][r]);
                    size_t base = (size_t)(b * 16 + h) * 131072 + (size_t)(tt >> 5) * 2048
                                + (size_t)d * 32 + (tt & 31);
                    *(v4s*)(Vp + base) = pk;
                }
        }
    }
}

// ---------------- flash attention: 2 waves/block, 64 q/block, s-split x2 ----------------
// S^T = K*Q^T (stats lane-local in q). No-max exp2 softmax. K/V prefetched 2 steps
// ahead via asm global_load_dwordx4; legalizer-invisible -> only OUR vmcnt waits.
#define ISSUE_LOAD(dst, ptr) \
    asm volatile("global_load_dwordx4 %0, %1, off" : "=v"(dst) : "v"(ptr))
#define WAIT_VM8(sl) \
    asm volatile("s_waitcnt vmcnt(8)" \
        : "+v"(kf[sl][0][0]), "+v"(kf[sl][0][1]), "+v"(kf[sl][1][0]), "+v"(kf[sl][1][1]), \
          "+v"(vf[sl][0]), "+v"(vf[sl][1]), "+v"(vf[sl][2]), "+v"(vf[sl][3]))
#define WAIT_VM0(sl) \
    asm volatile("s_waitcnt vmcnt(0)" \
        : "+v"(kf[sl][0][0]), "+v"(kf[sl][0][1]), "+v"(kf[sl][1][0]), "+v"(kf[sl][1][1]), \
          "+v"(vf[sl][0]), "+v"(vf[sl][1]), "+v"(vf[sl][2]), "+v"(vf[sl][3]))

__global__ __launch_bounds__(128) void attn(const ushort_t* __restrict__ Qr,
                                            const ushort_t* __restrict__ Kr,
                                            const ushort_t* __restrict__ Vt,
                                            ushort_t* __restrict__ AO) {
    __shared__ __align__(16) ushort_t P[2 * 2560];   // per-wave P [q 64][s 32 pad 40]
    __shared__ __align__(16) float MO[64 * 68];
    __shared__ float Mli[64];
    int tid = threadIdx.x, lane = tid & 63, W = tid >> 6;
    int lr = lane & 15, lc = lane >> 4;
    int L = blockIdx.x;                  // 1024 blocks
    int xcd = L & 7, slot = L >> 3;
    int bh = xcd * 4 + (slot >> 5);
    int q0 = (slot & 31) * 64;
    int b = bh >> 4, h = bh & 15;
    const ushort_t* Qb = Qr + ((size_t)bh * 2048 + q0) * 64;
    const ushort_t* Kp = Kr + (size_t)bh * 131072 + (size_t)W * 65536 + lr * 64 + lc * 8;
    const ushort_t* Vp = Vt + (size_t)bh * 131072 + (size_t)W * 65536 + lr * 32 + lc * 8;
    ushort_t* Pw = P + W * 2560;

    v8s qf[4][2];
    #pragma unroll
    for (int jq = 0; jq < 4; ++jq)
        #pragma unroll
        for (int kk = 0; kk < 2; ++kk)
            qf[jq][kk] = *(const v8s*)(Qb + (size_t)(jq * 16 + lr) * 64 + kk * 32 + lc * 8);

    v4f o[4][4] = {};
    float li[4] = {0.f, 0.f, 0.f, 0.f};
    v8s kf[2][2][2], vf[2][4];

    auto issueK = [&](int sl, int stp) {
        #pragma unroll
        for (int hh = 0; hh < 2; ++hh)
            #pragma unroll
            for (int kk = 0; kk < 2; ++kk) {
                const ushort_t* p = Kp + (size_t)stp * 2048 + hh * 1024 + kk * 32;
                if (sl == 0) ISSUE_LOAD(kf[0][hh][kk], p);
                else         ISSUE_LOAD(kf[1][hh][kk], p);
            }
    };
    auto issueV = [&](int sl, int stp) {
        #pragma unroll
        for (int i = 0; i < 4; ++i) {
            const ushort_t* p = Vp + (size_t)stp * 2048 + i * 512;
            if (sl == 0) ISSUE_LOAD(vf[0][i], p);
            else         ISSUE_LOAD(vf[1][i], p);
        }
    };
    auto step = [&](v8s (&kfs)[2][2], v8s (&vfs)[4]) {
        v4f St[2][4] = {};
        #pragma unroll
        for (int hh = 0; hh < 2; ++hh)
            #pragma unroll
            for (int jq = 0; jq < 4; ++jq) {
                St[hh][jq] = MFMA(kfs[hh][0], qf[jq][0], St[hh][jq]);
                St[hh][jq] = MFMA(kfs[hh][1], qf[jq][1], St[hh][jq]);
            }
        #pragma unroll
        for (int jq = 0; jq < 4; ++jq)
            #pragma unroll
            for (int hh = 0; hh < 2; ++hh) {
                #pragma unroll
                for (int r = 0; r < 4; ++r) {
                    float ev = __builtin_amdgcn_exp2f(St[hh][jq][r]);
                    St[hh][jq][r] = ev;
                    li[jq] += ev;
                }
                unsigned d0 = __builtin_amdgcn_perm(__float_as_uint(St[hh][jq][1]),
                                                    __float_as_uint(St[hh][jq][0]), 0x07060302u);
                unsigned d1 = __builtin_amdgcn_perm(__float_as_uint(St[hh][jq][3]),
                                                    __float_as_uint(St[hh][jq][2]), 0x07060302u);
                v2u pk = {d0, d1};
                *(v2u*)(Pw + (jq * 16 + lr) * 40 + hh * 16 + lc * 4) = pk;
            }
        __builtin_amdgcn_s_waitcnt(0xc07f);   // lgkmcnt(0) only; vm prefetch stays in flight
        #pragma unroll
        for (int jq = 0; jq < 4; ++jq) {
            v8s pf = *(const v8s*)(Pw + (jq * 16 + lr) * 40 + lc * 8);
            #pragma unroll
            for (int i = 0; i < 4; ++i)
                o[i][jq] = MFMA(vfs[i], pf, o[i][jq]);
        }
    };

    issueK(0, 0); issueV(0, 0);
    issueK(1, 1); issueV(1, 1);
    #pragma unroll 1
    for (int stp = 0; stp < 32; stp += 2) {
        WAIT_VM8(0);                               // outstanding 16 -> slot0 (oldest 8) done
        step(kf[0], vf[0]);
        if (stp + 2 < 32) { issueK(0, stp + 2); issueV(0, stp + 2); }
        if (stp + 3 < 32) { WAIT_VM8(1); } else { WAIT_VM0(1); }
        step(kf[1], vf[1]);
        if (stp + 3 < 32) { issueK(1, stp + 3); issueV(1, stp + 3); }
    }

    #pragma unroll
    for (int jq = 0; jq < 4; ++jq) {
        li[jq] += __shfl_xor(li[jq], 16);
        li[jq] += __shfl_xor(li[jq], 32);
    }
    if (W == 1) {
        #pragma unroll
        for (int jq = 0; jq < 4; ++jq) {
            #pragma unroll
            for (int i = 0; i < 4; ++i)
                *(v4f*)(MO + (jq * 16 + lr) * 68 + i * 16 + lc * 4) = o[i][jq];
            if (lc == 0) Mli[jq * 16 + lr] = li[jq];
        }
    }
    __syncthreads();
    if (W == 0) {
        #pragma unroll
        for (int jq = 0; jq < 4; ++jq) {
            float inv = 1.0f / (li[jq] + Mli[jq * 16 + lr]);
            int t = q0 + jq * 16 + lr;
            #pragma unroll
            for (int i = 0; i < 4; ++i) {
                v4f m = *(const v4f*)(MO + (jq * 16 + lr) * 68 + i * 16 + lc * 4);
                v4s pk;
                #pragma unroll
                for (int r = 0; r < 4; ++r) pk[r] = f2bf((o[i][jq][r] + m[r]) * inv);
                *(v4s*)(AO + (size_t)(b * 2048 + t) * 1024 + h * 64 + i * 16 + lc * 4) = pk;
            }
        }
    }
}

extern "C" void kernel_launch(void* const* d_in, const int* in_sizes, int n_in,
                              void* d_out, int out_size, void* d_ws, size_t ws_size,
                              hipStream_t stream) {
    char* ws = (char*)d_ws;
    int*      flag  = (int*)ws;                      // 256 B
    ushort_t* wqkvT = (ushort_t*)(ws + 256);         // 6 MB
    ushort_t* woT   = (ushort_t*)(ws + 6291712);     // 2 MB
    ushort_t* xb    = (ushort_t*)(ws + 8388864);     // 8 MB
    ushort_t* Qr    = (ushort_t*)(ws + 16777472);    // 8 MB
    ushort_t* Kr    = (ushort_t*)(ws + 25166080);    // 8 MB
    ushort_t* Vt    = (ushort_t*)(ws + 33554688);    // 8 MB
    ushort_t* AO    = (ushort_t*)(ws + 41943296);    // 8 MB
    float*    tab   = (float*)(ws + 50331904);       // 512 KB
    // total ~50.9 MB

    detect_dtype<<<1, 256, 0, stream>>>((const unsigned*)d_in[0], flag);
    rope_table<<<256, 256, 0, stream>>>(tab);
    cvt_x<<<2048, 256, 0, stream>>>(d_in[0], xb, flag, 524288);
    dim3 tb(32, 8);
    cvt_transpose<<<dim3(96, 32), tb, 0, stream>>>(d_in[1], wqkvT, flag, 1024, 3072);
    cvt_transpose<<<dim3(32, 32), tb, 0, stream>>>(d_in[2], woT, flag, 1024, 1024);
    gemm_bt<2><<<dim3(24, 32), 256, 0, stream>>>(xb, wqkvT, nullptr, flag, 4096, 3072, 1024,
                                                 Qr, Kr, Vt, tab);
    attn<<<1024, 128, 0, stream>>>(Qr, Kr, Vt, AO);
    gemm_bt<1><<<dim3(8, 32), 256, 0, stream>>>(AO, woT, d_out, flag, 4096, 1024, 1024,
                                                nullptr, nullptr, nullptr, nullptr);
}